// Round 2
// baseline (16346.465 us; speedup 1.0000x reference)
//
#include <hip/hip_runtime.h>
#include <stdint.h>

// BiLSTM fused: B=64, T=1024, D=256, H=256/dir, O=64. In fp32, out fp32.
// R11 passed @14.1ms: removing barriers/RMW/tid0-funnel saved only 0.6us/step
// -> the ~6.9us/step lived in the TRANSPORT: producer vmcnt(0) drain of
// write-through stores to false-shared lines (each 128B line of hist[t][b][:]
// received 8B stores from 4 different WGs, serialized at the coherent point),
// plus a second flag round trip. R12 removes all of it:
//   - SENTINEL EXCHANGE, no flags, no drain: h buffers pre-filled with 0xFF
//     (bf16 NaN, unreachable: gates clamped => |h|<1). Producers fire 8B
//     agent-scope atomic stores and move on. Consumers poll their own 16 data
//     words (relaxed agent atomic loads, bypass L2) until non-sentinel; a
//     word is either sentinel or final (single writer, written once), checked
//     per-dword (robust to 4B tearing). No ordering required at all.
//   - exchange layout [t][16 g][4 w][16 b][16 j] bf16: each 512B slot written
//     by exactly ONE wave -> no cross-WG line sharing on publish.
//   - both layers stream Wih (bf16, pre-converted) from L2; Whh stays in
//     VGPRs (it feeds the post-poll critical-path MFMAs). Frees the 128
//     VGPRs layer-0 used for resident Wih, paying for the 32-VGPR poll buf.
//
// Structure: 32 WGs per layer (2 dirs x 16 hidden-slices g); WG g owns hidden
// cols j in [16g,16g+16) == gate rows {j,256+j,512+j,768+j}.
//   acc[gate] = bias + Wih @ x[t]^T + Whh @ h[t-1]^T      (D[j][b], fp32 acc)
//
// Memory plan: d_ws = h0 exch [2][T][16][4][16][16] bf16 (64MB).
//   x buf (d_in[0], fp32, 64MB, dead after layer-0) -> h1 bf16 (exact fit),
//   sentinel-filled between layer kernels (stream-ordered).
//   d_out (16MB): [0,2MB) wb1 = Wih_l1 bf16 | [2MB,3MB) wb0 = Wih_l0 bf16.
//   FC head runs last, overwrites all of d_out.

typedef __attribute__((ext_vector_type(8))) short short8;   // 8 x bf16
typedef __attribute__((ext_vector_type(4))) float floatx4;  // MFMA acc

#define MFMA_BF16(A, B, C) __builtin_amdgcn_mfma_f32_16x16x32_bf16(A, B, C, 0, 0, 0)

__device__ __forceinline__ unsigned short f2bf(float f) {
  unsigned u = __float_as_uint(f);
  u += 0x7FFFu + ((u >> 16) & 1u);  // RNE
  return (unsigned short)(u >> 16);
}
__device__ __forceinline__ short8 load_cvt8(const float* p) {
  short8 r;
#pragma unroll
  for (int i = 0; i < 8; ++i) r[i] = (short)f2bf(p[i]);
  return r;
}
// NaN-killing clamps; inert for legit values (|gate preact| <~ 5, fc <~ 0.6).
__device__ __forceinline__ float clamp_gate(float x) { return fminf(30.f, fmaxf(-30.f, x)); }
__device__ __forceinline__ float clamp_fc(float x) { return fminf(4.f, fmaxf(-30.f, x)); }
__device__ __forceinline__ float sigm(float x) { return 1.0f / (1.0f + __expf(-x)); }
__device__ __forceinline__ float tanh_fast(float x) { return 1.0f - 2.0f / (1.0f + __expf(2.0f * x)); }

// Word is valid iff neither dword is all-ones (real bf16 h is never 0xFFFF:
// that's a NaN encoding and gates are clamped). Per-dword check is robust
// even if an 8B store were split into 4B pieces somewhere in the fabric.
__device__ __forceinline__ bool wok(unsigned long long v) {
  return ((unsigned)v != 0xFFFFFFFFu) & ((unsigned)(v >> 32) != 0xFFFFFFFFu);
}

// ---------------------------------------------------------------------------
// fp32 -> bf16 conversion (two regions), grid-strided.
// ---------------------------------------------------------------------------
__global__ __launch_bounds__(256) void cvt_kernel(
    const float* __restrict__ s0, unsigned short* __restrict__ d0, int n0,
    const float* __restrict__ s1, unsigned short* __restrict__ d1, int n1) {
  const int stride = gridDim.x * 256;
  for (int j = blockIdx.x * 256 + threadIdx.x; j < n0; j += stride) d0[j] = f2bf(s0[j]);
  for (int j = blockIdx.x * 256 + threadIdx.x; j < n1; j += stride) d1[j] = f2bf(s1[j]);
}

// ---------------------------------------------------------------------------
// One bidirectional LSTM layer, fused input GEMM + recurrence.
// LAYER=0: input = x fp32 [B][T][256] (per-step cvt), K=256.
// LAYER=1: input = h0 exch layout bf16 (K=512 concat of 2 dirs).
// Both layers stream Wih bf16 from cache; Whh lives in VGPRs.
// Exchange layout per dir: [1024 t][16 g][4 w][16 b_l][16 j_l] bf16.
// ---------------------------------------------------------------------------
template <int LAYER>
__global__ __launch_bounds__(256, 1) void lstm_layer_kernel(
    const float* __restrict__ xf32,          // LAYER 0 input
    const unsigned short* __restrict__ xbf,  // LAYER 1 input (h0, exch layout)
    const unsigned short* __restrict__ wih,  // bf16 [2][1024][KDIM]
    const float* __restrict__ WhhF, const float* __restrict__ WhhB,
    const float* __restrict__ bF, const float* __restrict__ bB,
    unsigned short* __restrict__ hout) {     // exch layout [2][...]
  constexpr int NKS = LAYER ? 16 : 8;
  constexpr int KDIM = NKS * 32;

  const int bx = blockIdx.x;
  const int dir = bx >> 4;
  const int g = bx & 15;
  const int tid = threadIdx.x;
  const int w = tid >> 6, l = tid & 63, l15 = l & 15, q = l >> 4;

  const float* Whh = dir ? WhhB : WhhF;
  const float* bias = dir ? bB : bF;

  // Whh A-fragments: cvt fp32 -> bf16 once (lane l15 -> j-row, q -> k-quad).
  short8 whh[4][8];
#pragma unroll
  for (int gi = 0; gi < 4; ++gi) {
    const float* wr = Whh + (size_t)(gi * 256 + g * 16 + l15) * 256;
#pragma unroll
    for (int ks = 0; ks < 8; ++ks) whh[gi][ks] = load_cvt8(wr + ks * 32 + q * 8);
  }

  const unsigned short* wd = wih + (size_t)dir * 1024 * KDIM;

  // Bias (fp32) for this lane's 16 outputs (gi, r) at j = g*16 + q*4 + r.
  float bvp[16];
#pragma unroll
  for (int gi = 0; gi < 4; ++gi)
#pragma unroll
    for (int r = 0; r < 4; ++r) bvp[gi * 4 + r] = bias[gi * 256 + g * 16 + q * 4 + r];

  const int b = w * 16 + l15;  // batch index this lane feeds (B-fragment)
  unsigned short* hd = hout + (size_t)dir * 1024 * 16384;  // 32MB/dir (shorts)

  float c[4] = {0.f, 0.f, 0.f, 0.f};

  for (int it = 0; it < 1024; ++it) {
    const int t = dir ? (1023 - it) : it;
    const int tp = dir ? (t + 1) : (t - 1);

    floatx4 acc[4];
#pragma unroll
    for (int gi = 0; gi < 4; ++gi)
#pragma unroll
      for (int r = 0; r < 4; ++r) acc[gi][r] = bvp[gi * 4 + r];

    // ---- x-part (independent of h[t-1]; overlaps peers' publish) ----
#pragma unroll
    for (int ks = 0; ks < NKS; ++ks) {
      short8 xf;
      if (LAYER == 0) {
        xf = load_cvt8(xf32 + (((size_t)b << 10) + t) * 256 + ks * 32 + q * 8);
      } else {
        const int kk2 = ks * 2 + (q >> 1);  // 0..31: [dir_in|g'] of k-range
        const size_t off = (size_t)(kk2 >> 4) * (1024 * 16384) +
                           (size_t)t * 16384 + (size_t)(kk2 & 15) * 1024 +
                           (size_t)w * 256 + l15 * 16 + (q & 1) * 8;
        xf = *(const short8*)(xbf + off);
      }
#pragma unroll
      for (int gi = 0; gi < 4; ++gi) {
        const short8 wfrag = *(const short8*)(
            wd + (size_t)(gi * 256 + g * 16 + l15) * KDIM + ks * 32 + q * 8);
        acc[gi] = MFMA_BF16(wfrag, xf, acc[gi]);
      }
    }

    // ---- recurrent part: poll the data words themselves ----
    if (it > 0) {
      // Lane's 8 B-fragments (16B each = 2 words) live at slots
      // (g' = ks*2 + (q>>1), w), byte offset b_l*32 + (q&1)*16.
      const unsigned short* hpp = hd + (size_t)tp * 16384 +
                                  (size_t)(q >> 1) * 1024 + (size_t)w * 256 +
                                  l15 * 16 + (q & 1) * 8;
      unsigned long long hwv[16];
#pragma unroll
      for (int i = 0; i < 16; ++i) hwv[i] = 0xFFFFFFFFFFFFFFFFull;
      for (;;) {
        bool ok = true;
#pragma unroll
        for (int ks = 0; ks < 8; ++ks) {
          const unsigned long long* p =
              (const unsigned long long*)(hpp + (size_t)ks * 2048);
          if (!wok(hwv[2 * ks]))
            hwv[2 * ks] = __hip_atomic_load(p, __ATOMIC_RELAXED,
                                            __HIP_MEMORY_SCOPE_AGENT);
          if (!wok(hwv[2 * ks + 1]))
            hwv[2 * ks + 1] = __hip_atomic_load(p + 1, __ATOMIC_RELAXED,
                                                __HIP_MEMORY_SCOPE_AGENT);
          ok = ok && wok(hwv[2 * ks]) && wok(hwv[2 * ks + 1]);
        }
        if (__all(ok)) break;
        __builtin_amdgcn_s_sleep(1);
      }
#pragma unroll
      for (int ks = 0; ks < 8; ++ks) {
        short8 hf;
        ((unsigned long long*)&hf)[0] = hwv[2 * ks];
        ((unsigned long long*)&hf)[1] = hwv[2 * ks + 1];
#pragma unroll
        for (int gi = 0; gi < 4; ++gi) acc[gi] = MFMA_BF16(whh[gi][ks], hf, acc[gi]);
      }
    }

    // ---- gates (i,f,g,o all in this lane) ----
    unsigned long long hv = 0ull;
#pragma unroll
    for (int r = 0; r < 4; ++r) {
      const float si = sigm(clamp_gate(acc[0][r]));
      const float sf = sigm(clamp_gate(acc[1][r]));
      const float tg = tanh_fast(clamp_gate(acc[2][r]));
      const float so = sigm(clamp_gate(acc[3][r]));
      const float cn = sf * c[r] + si * tg;
      c[r] = cn;
      const unsigned short hb16 = f2bf(so * tanh_fast(cn));
      hv |= ((unsigned long long)hb16) << (16 * r);
    }

    // ---- publish h: fire-and-forget write-through store. No drain, no flag.
    // Slot (g, w) is written only by this wave; word validity is the signal.
    __hip_atomic_store(
        (unsigned long long*)(hd + (size_t)t * 16384 + (size_t)g * 1024 +
                              (size_t)w * 256 + l15 * 16 + q * 4),
        hv, __ATOMIC_RELAXED, __HIP_MEMORY_SCOPE_AGENT);
    __builtin_amdgcn_sched_barrier(0);  // keep the store prompt (issue order)
  }
}

// ---------------------------------------------------------------------------
// FC head: out[b][t][o] = exp(h1concat[t][b][:] @ fc_W[o][:]^T + fc_b[o])
// h1 is in exch layout. fc_W fp32 -> bf16 into LDS once per block. Grid 1024
// x 256thr; block covers 64 rows (m = b*1024+t). OUTPUT FP32.
// ---------------------------------------------------------------------------
__global__ __launch_bounds__(256) void fc_head_kernel(
    const unsigned short* __restrict__ h1,  // exch layout [2][...] bf16
    const float* __restrict__ fcW,          // [64][512] fp32
    const float* __restrict__ fcb,          // [64] fp32
    float* __restrict__ out) {              // [B][T][64] fp32
  __shared__ unsigned short sW[64 * 512];
  const int tid = threadIdx.x;
  for (int i = tid; i < 64 * 512; i += 256) sW[i] = f2bf(fcW[i]);
  __syncthreads();

  const int w = tid >> 6, l = tid & 63, l15 = l & 15, q = l >> 4;
  const int m0 = blockIdx.x * 64 + w * 16;

  const int mA = m0 + l15;
  const int bA = mA >> 10, tA = mA & 1023;
  // Lane's A-row base within a dir: slot (g', w=bA>>4), b_l = bA&15.
  const size_t arow = (size_t)tA * 16384 + (size_t)(bA >> 4) * 256 +
                      (size_t)(bA & 15) * 16 + (q & 1) * 8;

  floatx4 acc[4];
#pragma unroll
  for (int nt = 0; nt < 4; ++nt) acc[nt] = (floatx4){0.f, 0.f, 0.f, 0.f};

#pragma unroll
  for (int dh = 0; dh < 2; ++dh) {
    const unsigned short* ad = h1 + (size_t)dh * (1024 * 16384);
#pragma unroll
    for (int ks = 0; ks < 8; ++ks) {
      const int gp = ks * 2 + (q >> 1);
      short8 af = *(const short8*)(ad + arow + (size_t)gp * 1024);
#pragma unroll
      for (int nt = 0; nt < 4; ++nt) {
        short8 bf = *(const short8*)(sW + (nt * 16 + l15) * 512 + dh * 256 +
                                     ks * 32 + q * 8);
        acc[nt] = MFMA_BF16(af, bf, acc[nt]);
      }
    }
  }

#pragma unroll
  for (int nt = 0; nt < 4; ++nt) {
    const float bv = fcb[nt * 16 + l15];
#pragma unroll
    for (int r = 0; r < 4; ++r) {
      const int m = m0 + q * 4 + r;
      out[(size_t)m * 64 + nt * 16 + l15] = __expf(clamp_fc(acc[nt][r] + bv));
    }
  }
}

// ---------------------------------------------------------------------------
__global__ void diag_kernel(float* out, int n, float code) {
  int i = blockIdx.x * 256 + threadIdx.x;
  if (i < n) out[i] = (i == 0) ? code : 1.0f;
}

// ---------------------------------------------------------------------------

extern "C" void kernel_launch(void* const* d_in, const int* in_sizes, int n_in,
                              void* d_out, int out_size, void* d_ws, size_t ws_size,
                              hipStream_t stream) {
  const float* x       = (const float*)d_in[0];
  const float* Wih_l0f = (const float*)d_in[1];
  const float* Whh_l0f = (const float*)d_in[2];
  const float* b_l0f   = (const float*)d_in[3];
  const float* Wih_l0b = (const float*)d_in[4];
  const float* Whh_l0b = (const float*)d_in[5];
  const float* b_l0b   = (const float*)d_in[6];
  const float* Wih_l1f = (const float*)d_in[7];
  const float* Whh_l1f = (const float*)d_in[8];
  const float* b_l1f   = (const float*)d_in[9];
  const float* Wih_l1b = (const float*)d_in[10];
  const float* Whh_l1b = (const float*)d_in[11];
  const float* b_l1b   = (const float*)d_in[12];
  const float* fc_W    = (const float*)d_in[13];
  const float* fc_b    = (const float*)d_in[14];
  float* out = (float*)d_out;

  const size_t H_BYTES = (size_t)2 * 1024 * 64 * 256 * 2;  // 64MB

  if (ws_size < H_BYTES) {
    diag_kernel<<<dim3((out_size + 255) / 256), dim3(256), 0, stream>>>(
        out, out_size, 200.0f + (float)(ws_size >> 20));
    return;
  }

  unsigned short* h0 = (unsigned short*)d_ws;     // exch layout, 64MB
  unsigned short* h1 = (unsigned short*)d_in[0];  // x buf (fp32, 64MB): dead
                                                  // after layer-0 -> h1 bf16
  // d_out: [0,2MB) wb1 = Wih_l1 bf16 | [2MB,3MB) wb0 = Wih_l0 bf16.
  unsigned short* wb1 = (unsigned short*)d_out;
  unsigned short* wb0 = (unsigned short*)((uint8_t*)d_out + (2u << 20));

  // Sentinel-fill h0 (h1 gets filled after layer-0 frees the x buffer).
  hipMemsetAsync(h0, 0xFF, H_BYTES, stream);

  // Wih fp32 -> bf16 into d_out's dead prefix.
  cvt_kernel<<<dim3(512), dim3(256), 0, stream>>>(
      Wih_l1f, wb1, 1024 * 512, Wih_l1b, wb1 + (size_t)1024 * 512, 1024 * 512);
  cvt_kernel<<<dim3(512), dim3(256), 0, stream>>>(
      Wih_l0f, wb0, 1024 * 256, Wih_l0b, wb0 + (size_t)1024 * 256, 1024 * 256);

  lstm_layer_kernel<0><<<dim3(32), dim3(256), 0, stream>>>(
      x, nullptr, wb0, Whh_l0f, Whh_l0b, b_l0f, b_l0b, h0);
  hipMemsetAsync(h1, 0xFF, H_BYTES, stream);  // stream-ordered after layer-0
  lstm_layer_kernel<1><<<dim3(32), dim3(256), 0, stream>>>(
      nullptr, h0, wb1, Whh_l1f, Whh_l1b, b_l1f, b_l1b, h1);
  fc_head_kernel<<<dim3(1024), dim3(256), 0, stream>>>(h1, fc_W, fc_b, out);
}